// Round 6
// baseline (554.140 us; speedup 1.0000x reference)
//
#include <hip/hip_runtime.h>
#include <hip/hip_bf16.h>

// Problem dims (fixed)
#define B_ 2
#define L_ 2048
#define D_ 1024
#define E_ 2048
#define N_ 16
#define DR_ 64
#define DC_ 4
#define M_ (B_*L_)   // 4096 rows
#define SSEG 64      // scan segments
#define LSEG 32      // timesteps per segment
#define KS_ 8        // split-K factor for C96 GEMM

typedef __attribute__((ext_vector_type(8))) short bf16x8;
typedef __attribute__((ext_vector_type(4))) float f32x4;

__device__ __forceinline__ ushort f2bf(float x){
    union { float f; unsigned u; } v; v.f = x;
    unsigned r = v.u + 0x7FFFu + ((v.u >> 16) & 1u);
    return (ushort)(r >> 16);
}
__device__ __forceinline__ float bf2f(ushort u){
    union { unsigned u; float f; } v; v.u = ((unsigned)u) << 16;
    return v.f;
}

// async global->LDS, 16B per lane. LDS dest = wave-uniform base + lane*16.
__device__ __forceinline__ void gld16(const void* g, void* l){
    __builtin_amdgcn_global_load_lds(
        (const __attribute__((address_space(1))) unsigned int*)g,
        (__attribute__((address_space(3))) unsigned int*)l,
        16, 0, 0);
}

__device__ __forceinline__ float sel4(int i, float a, float b, float c, float d){
    float r = (i == 1) ? b : a;
    r = (i == 2) ? c : r;
    r = (i == 3) ? d : r;
    return r;
}

// ---------------- convert f32 -> bf16 (vec4) ----------------
__global__ void cvt4_k(const float* __restrict__ in, ushort* __restrict__ out, int n4){
    int i = blockIdx.x * 256 + threadIdx.x;
    if (i < n4){
        float4 v = ((const float4*)in)[i];
        ushort4 o;
        o.x = f2bf(v.x); o.y = f2bf(v.y); o.z = f2bf(v.z); o.w = f2bf(v.w);
        ((ushort4*)out)[i] = o;
    }
}

__global__ void zero16_k(ushort* __restrict__ p, int n){
    int i = blockIdx.x * 256 + threadIdx.x;
    if (i < n) p[i] = 0;
}

// ---------------- RMSNorm -> bf16 ----------------
__global__ __launch_bounds__(256) void rmsnorm_k(const float* __restrict__ resid,
                                                 const float* __restrict__ norm_w,
                                                 ushort* __restrict__ xn){
    int row = blockIdx.x;
    const float4* r = (const float4*)(resid + (size_t)row * D_);
    float4 v = r[threadIdx.x];
    float ss = v.x*v.x + v.y*v.y + v.z*v.z + v.w*v.w;
    for (int m = 32; m; m >>= 1) ss += __shfl_xor(ss, m);
    __shared__ float sred[4];
    if ((threadIdx.x & 63) == 0) sred[threadIdx.x >> 6] = ss;
    __syncthreads();
    float tot = sred[0] + sred[1] + sred[2] + sred[3];
    float scale = rsqrtf(tot / (float)D_ + 1e-5f);
    const float4* wv = (const float4*)norm_w;
    float4 w = wv[threadIdx.x];
    ushort4 o;
    o.x = f2bf(v.x * scale * w.x);
    o.y = f2bf(v.y * scale * w.y);
    o.z = f2bf(v.z * scale * w.z);
    o.w = f2bf(v.w * scale * w.w);
    ((ushort4*)(xn + (size_t)row * D_))[threadIdx.x] = o;
}

// ---------------- GEMM: C[M,N] = A[M,K] * B[N,K]^T, bf16 in, f32 acc ----------------
// global_load_lds width-16 staging into LINEAR LDS [128][64] (m97 structure).
// EPI: 1 = bf16 store, 3 = acc + aux[idx] f32 store
#define BM 128
#define BN 128
#define BK 64

template<int EPI>
__global__ __launch_bounds__(256)
void gemm_bt(const ushort* __restrict__ A, const ushort* __restrict__ Bm,
             void* __restrict__ Cp, const float* __restrict__ aux,
             int M, int N, int K, int lda, int ldb, int ldc){
    __shared__ __align__(16) ushort As[BM * BK];
    __shared__ __align__(16) ushort Bs[BN * BK];
    const int col0 = blockIdx.x * BN;
    const int row0 = blockIdx.y * BM;
    const int tid = threadIdx.x;
    const int lane = tid & 63;
    const int wid = tid >> 6;
    const int wm = wid >> 1, wn = wid & 1;   // 2x2 waves of 64x64
    f32x4 acc[4][4] = {};

    const int l8 = lane >> 3;        // row within 8-row group
    const int c8 = (lane & 7) * 8;   // col (elements)

    for (int k0 = 0; k0 < K; k0 += BK){
        #pragma unroll
        for (int i = 0; i < 4; ++i){
            const int R0 = wid * 32 + i * 8;   // 8 rows per instr
            gld16(A + (size_t)(row0 + R0 + l8) * lda + k0 + c8, As + R0 * BK);
            gld16(Bm + (size_t)(col0 + R0 + l8) * ldb + k0 + c8, Bs + R0 * BK);
        }
        __syncthreads();   // drains vmcnt before barrier
        #pragma unroll
        for (int kk = 0; kk < 2; ++kk){
            bf16x8 af[4], bfr[4];
            const int krow = lane & 15;
            const int kcol = kk * 32 + (lane >> 4) * 8;
            #pragma unroll
            for (int mi = 0; mi < 4; ++mi)
                af[mi] = *(const bf16x8*)(As + (wm*64 + mi*16 + krow) * BK + kcol);
            #pragma unroll
            for (int ni = 0; ni < 4; ++ni)
                bfr[ni] = *(const bf16x8*)(Bs + (wn*64 + ni*16 + krow) * BK + kcol);
            #pragma unroll
            for (int mi = 0; mi < 4; ++mi)
                #pragma unroll
                for (int ni = 0; ni < 4; ++ni)
                    acc[mi][ni] = __builtin_amdgcn_mfma_f32_16x16x32_bf16(af[mi], bfr[ni], acc[mi][ni], 0, 0, 0);
        }
        __syncthreads();
    }

    #pragma unroll
    for (int mi = 0; mi < 4; ++mi)
        #pragma unroll
        for (int ni = 0; ni < 4; ++ni)
            #pragma unroll
            for (int j = 0; j < 4; ++j){
                int r = row0 + wm*64 + mi*16 + (lane >> 4) * 4 + j;
                int c = col0 + wn*64 + ni*16 + (lane & 15);
                size_t idx = (size_t)r * ldc + c;
                float v = acc[mi][ni][j];
                if (EPI == 1){
                    ((ushort*)Cp)[idx] = f2bf(v);
                } else {
                    ((float*)Cp)[idx] = v + aux[idx];
                }
            }
}

// ---------------- C96 GEMM, split-K: part[ks][4096][128] f32 partials ----------------
__global__ __launch_bounds__(256)
void gemm_c96_sk(const ushort* __restrict__ A, const ushort* __restrict__ Bm,
                 float* __restrict__ part){
    __shared__ __align__(16) ushort As[BM * BK];
    __shared__ __align__(16) ushort Bs[BN * BK];
    const int ks = blockIdx.x;
    const int row0 = blockIdx.y * BM;
    const int tid = threadIdx.x;
    const int lane = tid & 63;
    const int wid = tid >> 6;
    const int wm = wid >> 1, wn = wid & 1;
    f32x4 acc[4][4] = {};
    const int l8 = lane >> 3;
    const int c8 = (lane & 7) * 8;

    for (int k0 = ks * (E_ / KS_); k0 < (ks + 1) * (E_ / KS_); k0 += BK){
        #pragma unroll
        for (int i = 0; i < 4; ++i){
            const int R0 = wid * 32 + i * 8;
            gld16(A + (size_t)(row0 + R0 + l8) * E_ + k0 + c8, As + R0 * BK);
            gld16(Bm + (size_t)(R0 + l8) * E_ + k0 + c8, Bs + R0 * BK);
        }
        __syncthreads();
        #pragma unroll
        for (int kk = 0; kk < 2; ++kk){
            bf16x8 af[4], bfr[4];
            const int krow = lane & 15;
            const int kcol = kk * 32 + (lane >> 4) * 8;
            #pragma unroll
            for (int mi = 0; mi < 4; ++mi)
                af[mi] = *(const bf16x8*)(As + (wm*64 + mi*16 + krow) * BK + kcol);
            #pragma unroll
            for (int ni = 0; ni < 4; ++ni)
                bfr[ni] = *(const bf16x8*)(Bs + (wn*64 + ni*16 + krow) * BK + kcol);
            #pragma unroll
            for (int mi = 0; mi < 4; ++mi)
                #pragma unroll
                for (int ni = 0; ni < 4; ++ni)
                    acc[mi][ni] = __builtin_amdgcn_mfma_f32_16x16x32_bf16(af[mi], bfr[ni], acc[mi][ni], 0, 0, 0);
        }
        __syncthreads();
    }
    float* dst = part + (size_t)ks * M_ * 128;
    #pragma unroll
    for (int mi = 0; mi < 4; ++mi)
        #pragma unroll
        for (int ni = 0; ni < 4; ++ni)
            #pragma unroll
            for (int j = 0; j < 4; ++j){
                int r = row0 + wm*64 + mi*16 + (lane >> 4) * 4 + j;
                int c = wn*64 + ni*16 + (lane & 15);
                dst[(size_t)r * 128 + c] = acc[mi][ni][j];
            }
}

// reduce split-K partials -> C96 bf16; also emit cols 64..95 as f32 (BCf) for the scan
__global__ __launch_bounds__(256) void c96_reduce_k(const float* __restrict__ part,
                                                    ushort* __restrict__ C96,
                                                    float* __restrict__ BCf){
    int i4 = blockIdx.x * 256 + threadIdx.x;     // over M_*128/4
    float4 a = *(const float4*)(part + (size_t)i4 * 4);
    #pragma unroll
    for (int k = 1; k < KS_; ++k){
        float4 b = *(const float4*)(part + (size_t)k * M_ * 128 + (size_t)i4 * 4);
        a.x += b.x; a.y += b.y; a.z += b.z; a.w += b.w;
    }
    ushort4 o;
    o.x = f2bf(a.x); o.y = f2bf(a.y); o.z = f2bf(a.z); o.w = f2bf(a.w);
    *(ushort4*)(C96 + (size_t)i4 * 4) = o;
    int idx = i4 * 4;
    int col = idx & 127;
    int row = idx >> 7;
    if (col >= 64 && col < 96)
        *(float4*)(BCf + (size_t)row * 32 + (col - 64)) = a;
}

// ---------------- causal depthwise conv1d + silu (vec4 along e) ----------------
__global__ __launch_bounds__(256) void conv_silu_k(const ushort* __restrict__ xpre,
                                                   const float* __restrict__ conv_w,
                                                   const float* __restrict__ conv_b,
                                                   float* __restrict__ xf,
                                                   ushort* __restrict__ xb){
    int i4 = blockIdx.x * 256 + threadIdx.x;
    if (i4 >= M_ * E_ / 4) return;
    int idx = i4 * 4;
    int e = idx & (E_ - 1);
    int bl = idx >> 11;
    int t = bl & (L_ - 1);
    float acc[4];
    #pragma unroll
    for (int j = 0; j < 4; ++j) acc[j] = conv_b[e + j];
    #pragma unroll
    for (int k = 0; k < 4; ++k){
        int dt = 3 - k;
        if (t >= dt){
            ushort4 xv = *(const ushort4*)(xpre + idx - dt * E_);
            acc[0] += bf2f(xv.x) * conv_w[(e+0)*4 + k];
            acc[1] += bf2f(xv.y) * conv_w[(e+1)*4 + k];
            acc[2] += bf2f(xv.z) * conv_w[(e+2)*4 + k];
            acc[3] += bf2f(xv.w) * conv_w[(e+3)*4 + k];
        }
    }
    float4 so; ushort4 sb;
    float* sp = (float*)&so;
    #pragma unroll
    for (int j = 0; j < 4; ++j){
        float s = acc[j] / (1.f + __expf(-acc[j]));
        sp[j] = s;
    }
    sb.x = f2bf(so.x); sb.y = f2bf(so.y); sb.z = f2bf(so.z); sb.w = f2bf(so.w);
    *(float4*)(xf + idx) = so;
    *(ushort4*)(xb + idx) = sb;
}

// ---------------- n-in-register chunk-parallel selective scan ----------------
// Thread owns one e, all 16 n-states in registers; wave = one 32-t segment x 64 e.
// Block = 4 waves = 4 consecutive segments; zero block barriers (per-wave staging).
// delta fused via MFMA (A = C96 xr rows, B = wd2 rows); MFMA output redistributed
// to owner lanes via 12-shfl rotation (static register indices only).
// PASS2: y output fused with gating -> y2 bf16.

template<int PASS2>
__global__ __launch_bounds__(256, 4)
void scan_k(const float* __restrict__ xf, const ushort* __restrict__ C96,
            const float* __restrict__ BCf, const ushort* __restrict__ wd2b,
            const float* __restrict__ wd2_bias, const float* __restrict__ A_log,
            const float* __restrict__ carr,
            float* __restrict__ F, float* __restrict__ segdt,
            const ushort* __restrict__ skipb, const float* __restrict__ W_D,
            ushort* __restrict__ y2)
{
    const int tid = threadIdx.x;
    const int w = tid >> 6, lane = tid & 63;
    const int q = lane >> 4, c = lane & 15;
    const int e0 = blockIdx.x * 64;
    const int g = blockIdx.y;          // seg-group: segs 4g..4g+3, t-window g*128..+128
    const int b = blockIdx.z;
    const int e = e0 + lane;
    const int seg = g * 4 + w;
    const size_t grow0 = (size_t)b * L_ + (size_t)g * 128;   // global row of window start

    __shared__ __align__(16) ushort sxr[128 * 64];   // [r][64]bf16; 16B-chunk XOR-swizzled
    __shared__ __align__(16) float  sBC[128 * 32];   // [r][B n0..15 | C n0..15] f32 linear

    // stage this wave's 32 rows (xr swizzled so MFMA b128 reads are conflict-free)
    #pragma unroll
    for (int k2 = 0; k2 < 4; ++k2){
        int R0 = w * 32 + k2 * 8;
        int r = R0 + (lane >> 3);
        int cc = (lane & 7) ^ (r & 7);
        gld16(C96 + (grow0 + r) * 128 + cc * 8, sxr + R0 * 64);
        gld16(BCf + (grow0 + r) * 32 + (lane & 7) * 4, sBC + R0 * 32);
    }
    asm volatile("s_waitcnt vmcnt(0)" ::: "memory");
    __builtin_amdgcn_sched_barrier(0);

    float Aen[16];
    {
        const float4* al = (const float4*)(A_log + (size_t)e * N_);
        #pragma unroll
        for (int g4 = 0; g4 < 4; ++g4){
            float4 v = al[g4];
            Aen[g4*4+0] = -__expf(v.x); Aen[g4*4+1] = -__expf(v.y);
            Aen[g4*4+2] = -__expf(v.z); Aen[g4*4+3] = -__expf(v.w);
        }
    }
    float h[16];
    if (PASS2){
        const float4* cp = (const float4*)(carr + ((size_t)(b * SSEG + seg) * E_ + e) * N_);
        #pragma unroll
        for (int g4 = 0; g4 < 4; ++g4){
            float4 v = cp[g4];
            h[g4*4+0] = v.x; h[g4*4+1] = v.y; h[g4*4+2] = v.z; h[g4*4+3] = v.w;
        }
    } else {
        #pragma unroll
        for (int n = 0; n < 16; ++n) h[n] = 0.f;
    }

    bf16x8 wfrag[4][2];
    #pragma unroll
    for (int m = 0; m < 4; ++m)
        #pragma unroll
        for (int kk = 0; kk < 2; ++kk)
            wfrag[m][kk] = *(const bf16x8*)(wd2b + (size_t)(e0 + m*16 + c) * DR_ + kk*32 + q*8);

    const float bias_e = wd2_bias[e];
    const float wde = PASS2 ? W_D[e] : 0.f;
    float sdt = 0.f;

    #pragma unroll
    for (int tt = 0; tt < 2; ++tt){
        const int tb = w * 32 + tt * 16;   // window row of tile base
        // --- fused delta: 8 MFMAs, D[t_in][e_in]: lane holds e_in=c, t_in=q*4+j, e-tile m
        f32x4 d0 = {}, d1 = {}, d2 = {}, d3 = {};
        #pragma unroll
        for (int kk = 0; kk < 2; ++kk){
            int r = tb + c;
            int chunk = kk * 4 + q;
            bf16x8 af = *(const bf16x8*)(sxr + r * 64 + ((chunk ^ (r & 7)) << 3));
            d0 = __builtin_amdgcn_mfma_f32_16x16x32_bf16(af, wfrag[0][kk], d0, 0, 0, 0);
            d1 = __builtin_amdgcn_mfma_f32_16x16x32_bf16(af, wfrag[1][kk], d1, 0, 0, 0);
            d2 = __builtin_amdgcn_mfma_f32_16x16x32_bf16(af, wfrag[2][kk], d2, 0, 0, 0);
            d3 = __builtin_amdgcn_mfma_f32_16x16x32_bf16(af, wfrag[3][kk], d3, 0, 0, 0);
        }
        // --- rotation-shuffle: lane l gathers its e's 16 t-values (m = q across quads)
        float rq0[4], rq1[4], rq2[4], rq3[4];
        #pragma unroll
        for (int j = 0; j < 4; ++j) rq0[j] = sel4(q, d0[j], d1[j], d2[j], d3[j]);
        {
            int src1 = (((q + 1) & 3) << 4) + c;
            int pi1 = (q - 1) & 3;
            int src2 = (((q + 2) & 3) << 4) + c;
            int pi2 = (q - 2) & 3;
            int src3 = (((q + 3) & 3) << 4) + c;
            int pi3 = (q - 3) & 3;
            #pragma unroll
            for (int j = 0; j < 4; ++j){
                rq1[j] = __shfl(sel4(pi1, d0[j], d1[j], d2[j], d3[j]), src1);
                rq2[j] = __shfl(sel4(pi2, d0[j], d1[j], d2[j], d3[j]), src2);
                rq3[j] = __shfl(sel4(pi3, d0[j], d1[j], d2[j], d3[j]), src3);
            }
        }
        // --- reorder to t-order + softplus (all static indices)
        float dts[16];
        #pragma unroll
        for (int p = 0; p < 4; ++p){
            int sp = (p - q) & 3;
            #pragma unroll
            for (int j = 0; j < 4; ++j){
                float z = sel4(sp, rq0[j], rq1[j], rq2[j], rq3[j]) + bias_e;
                float dt = (z > 20.f) ? z : log1pf(__expf(z));
                dts[p*4+j] = dt;
                if (!PASS2) sdt += dt;
            }
        }
        // --- scan 16 timesteps
        const float* xp = xf + (grow0 + tb) * E_ + e;
        const ushort* skp = skipb + (grow0 + tb) * E_ + e;
        ushort* yp = y2 + (grow0 + tb) * E_ + e;
        #pragma unroll
        for (int u = 0; u < 16; ++u){
            const float* bc = sBC + (tb + u) * 32;
            float dt = dts[u];
            float xu = xp[(size_t)u * E_];
            float dtx = dt * xu;
            float y0 = 0.f, y1 = 0.f;
            #pragma unroll
            for (int gg = 0; gg < 4; ++gg){
                float4 Bv = *(const float4*)(bc + gg * 4);
                h[gg*4+0] = __expf(dt * Aen[gg*4+0]) * h[gg*4+0] + dtx * Bv.x;
                h[gg*4+1] = __expf(dt * Aen[gg*4+1]) * h[gg*4+1] + dtx * Bv.y;
                h[gg*4+2] = __expf(dt * Aen[gg*4+2]) * h[gg*4+2] + dtx * Bv.z;
                h[gg*4+3] = __expf(dt * Aen[gg*4+3]) * h[gg*4+3] + dtx * Bv.w;
                if (PASS2){
                    float4 Cv = *(const float4*)(bc + 16 + gg * 4);
                    y0 += h[gg*4+0] * Cv.x + h[gg*4+1] * Cv.y;
                    y1 += h[gg*4+2] * Cv.z + h[gg*4+3] * Cv.w;
                }
            }
            if (PASS2){
                float sk = bf2f(skp[(size_t)u * E_]);
                float gsk = sk / (1.f + __expf(-sk));
                float yo = (y0 + y1 + wde * xu) * gsk;
                yp[(size_t)u * E_] = f2bf(yo);
            }
        }
    }
    if (!PASS2){
        float* Fp = F + ((size_t)(b * SSEG + seg) * E_ + e) * N_;
        #pragma unroll
        for (int g4 = 0; g4 < 4; ++g4){
            float4 v;
            v.x = h[g4*4+0]; v.y = h[g4*4+1]; v.z = h[g4*4+2]; v.w = h[g4*4+3];
            ((float4*)Fp)[g4] = v;
        }
        segdt[(size_t)(b * SSEG + seg) * E_ + e] = sdt;
    }
}

// sequential carry over SSEG segments per (b,e,n)
__global__ __launch_bounds__(256) void carry_k(const float* __restrict__ F,
                                               const float* __restrict__ segdt,
                                               const float* __restrict__ A_log,
                                               float* __restrict__ carr){
    int idx = blockIdx.x * 256 + threadIdx.x;      // over B_*E_*N_
    int n = idx & 15;
    int e = (idx >> 4) & (E_ - 1);
    int b = idx >> 15;
    const float Aen = -__expf(A_log[e * N_ + n]);
    float cacc = 0.f;
    for (int s = 0; s < SSEG; ++s){
        size_t base = ((size_t)(b * SSEG + s) * E_ + e) * N_ + n;
        carr[base] = cacc;
        float P = __expf(Aen * segdt[(size_t)(b * SSEG + s) * E_ + e]);
        cacc = P * cacc + F[base];
    }
}

// ---------------- launch ----------------
extern "C" void kernel_launch(void* const* d_in, const int* in_sizes, int n_in,
                              void* d_out, int out_size, void* d_ws, size_t ws_size,
                              hipStream_t stream){
    const float* resid  = (const float*)d_in[0];
    const float* norm_w = (const float*)d_in[1];
    const float* skip_w = (const float*)d_in[2];
    const float* in_w   = (const float*)d_in[3];
    const float* conv_w = (const float*)d_in[4];
    const float* conv_b = (const float*)d_in[5];
    const float* wd1    = (const float*)d_in[6];
    const float* wd2    = (const float*)d_in[7];
    const float* wd2_b  = (const float*)d_in[8];
    const float* wB     = (const float*)d_in[9];
    const float* wC     = (const float*)d_in[10];
    const float* A_log  = (const float*)d_in[11];
    const float* W_D    = (const float*)d_in[12];
    const float* out_w  = (const float*)d_in[13];
    float* out = (float*)d_out;

    char* ws = (char*)d_ws;
    size_t off = 0;
    auto alloc = [&](size_t bytes) -> char* {
        char* p = ws + off;
        off += (bytes + 255) & ~(size_t)255;
        return p;
    };
    // --- aliased region (32MB): wi, wsk, xn, xpre dead in stages; reused for
    //     split-K partials (16MB, dead after c96_reduce) then carr (16MB).
    char* alias_base = ws;
    ushort* wi_b    = (ushort*)alloc((size_t)E_ * D_ * 2);   // 4MB
    ushort* wsk_b   = (ushort*)alloc((size_t)E_ * D_ * 2);   // 4MB
    ushort* xn_b    = (ushort*)alloc((size_t)M_ * D_ * 2);   // 8MB
    ushort* xpre_b  = (ushort*)alloc((size_t)M_ * E_ * 2);   // 16MB
    float*  part_buf= (float*)alias_base;                    // 16MB alias (KS_*M_*128*4)
    float*  carr_buf= (float*)alias_base;                    // 16MB alias (after c96_reduce)
    // --- persistent buffers
    ushort* wo_b    = (ushort*)alloc((size_t)D_ * E_ * 2);       // 4MB
    ushort* wd2_bf  = (ushort*)alloc((size_t)E_ * DR_ * 2);      // 256KB
    ushort* W96_b   = (ushort*)alloc((size_t)128 * E_ * 2);      // 512KB
    ushort* skip_b  = (ushort*)alloc((size_t)M_ * E_ * 2);       // 16MB
    float*  xff     = (float*)alloc((size_t)M_ * E_ * 4);        // 32MB
    ushort* xb_b    = (ushort*)alloc((size_t)M_ * E_ * 2);       // 16MB
    ushort* C96_b   = (ushort*)alloc((size_t)M_ * 128 * 2);      // 1MB
    float*  scr     = (float*)alloc((size_t)M_ * E_ * 4);        // 32MB scratch slot
    ushort* y2_b    = (ushort*)alloc((size_t)M_ * E_ * 2);       // 16MB
    // sub-layout of scr: F (16MB) | segdt (1MB) | BCf (512KB)
    float* F_buf    = scr;
    float* segdt_buf= scr + (size_t)B_ * SSEG * E_ * N_;
    float* BCf_buf  = segdt_buf + (size_t)B_ * SSEG * E_;
    (void)ws_size; (void)in_sizes; (void)n_in; (void)out_size;

    const int thr = 256;
    auto blocks4 = [](int n){ return (n/4 + 255) / 256; };

    // weight conversions
    cvt4_k<<<blocks4(E_*D_), thr, 0, stream>>>(in_w,   wi_b,   E_*D_/4);
    cvt4_k<<<blocks4(E_*D_), thr, 0, stream>>>(skip_w, wsk_b,  E_*D_/4);
    cvt4_k<<<blocks4(D_*E_), thr, 0, stream>>>(out_w,  wo_b,   D_*E_/4);
    cvt4_k<<<blocks4(E_*DR_), thr, 0, stream>>>(wd2,   wd2_bf, E_*DR_/4);
    cvt4_k<<<blocks4(DR_*E_), thr, 0, stream>>>(wd1,   W96_b,            DR_*E_/4);
    cvt4_k<<<blocks4(N_*E_),  thr, 0, stream>>>(wB,    W96_b + 64*E_,    N_*E_/4);
    cvt4_k<<<blocks4(N_*E_),  thr, 0, stream>>>(wC,    W96_b + 80*E_,    N_*E_/4);
    zero16_k<<<(32*E_ + 255)/256, thr, 0, stream>>>(W96_b + 96*E_, 32*E_);

    // RMSNorm
    rmsnorm_k<<<M_, thr, 0, stream>>>(resid, norm_w, xn_b);

    // in-proj and skip-proj GEMMs: [4096,2048] = [4096,1024] x [2048,1024]^T
    gemm_bt<1><<<dim3(E_/BN, M_/BM), thr, 0, stream>>>(xn_b, wi_b,  xpre_b, nullptr, M_, E_, D_, D_, D_, E_);
    gemm_bt<1><<<dim3(E_/BN, M_/BM), thr, 0, stream>>>(xn_b, wsk_b, skip_b, nullptr, M_, E_, D_, D_, D_, E_);

    // conv + silu
    conv_silu_k<<<(M_*E_/4 + 255)/256, thr, 0, stream>>>(xpre_b, conv_w, conv_b, xff, xb_b);

    // C96[4096,128] = x[4096,2048] x W96[128,2048]^T, split-K x8 + reduce (+BCf f32)
    gemm_c96_sk<<<dim3(KS_, M_/BM), thr, 0, stream>>>(xb_b, W96_b, part_buf);
    c96_reduce_k<<<(M_*128/4)/256, thr, 0, stream>>>(part_buf, C96_b, BCf_buf);

    // chunk-parallel selective scan (n-in-register), gate fused into pass 2
    scan_k<0><<<dim3(E_/64, 16, B_), thr, 0, stream>>>(xff, C96_b, BCf_buf, wd2_bf, wd2_b, A_log,
                                                       nullptr, F_buf, segdt_buf, nullptr, nullptr, nullptr);
    carry_k<<<(B_*E_*N_)/256, thr, 0, stream>>>(F_buf, segdt_buf, A_log, carr_buf);
    scan_k<1><<<dim3(E_/64, 16, B_), thr, 0, stream>>>(xff, C96_b, BCf_buf, wd2_bf, wd2_b, A_log,
                                                       carr_buf, nullptr, nullptr, skip_b, W_D, y2_b);

    // out-proj + residual: out[4096,1024] = y2[4096,2048] x out_w[1024,2048]^T + resid
    gemm_bt<3><<<dim3(D_/BN, M_/BM), thr, 0, stream>>>(y2_b, wo_b, out, resid, M_, D_, E_, E_, E_, D_);
}

// Round 7
// 446.701 us; speedup vs baseline: 1.2405x; 1.2405x over previous
//
#include <hip/hip_runtime.h>
#include <hip/hip_bf16.h>

// Problem dims (fixed)
#define B_ 2
#define L_ 2048
#define D_ 1024
#define E_ 2048
#define N_ 16
#define DR_ 64
#define DC_ 4
#define M_ (B_*L_)   // 4096 rows
#define SSEG 64      // scan segments
#define LSEG 32      // timesteps per segment
#define KS_ 8        // split-K factor for C96 GEMM

typedef __attribute__((ext_vector_type(8))) short bf16x8;
typedef __attribute__((ext_vector_type(4))) float f32x4;

__device__ __forceinline__ ushort f2bf(float x){
    union { float f; unsigned u; } v; v.f = x;
    unsigned r = v.u + 0x7FFFu + ((v.u >> 16) & 1u);
    return (ushort)(r >> 16);
}
__device__ __forceinline__ float bf2f(ushort u){
    union { unsigned u; float f; } v; v.u = ((unsigned)u) << 16;
    return v.f;
}

// async global->LDS, 16B per lane. LDS dest = wave-uniform base + lane*16.
__device__ __forceinline__ void gld16(const void* g, void* l){
    __builtin_amdgcn_global_load_lds(
        (const __attribute__((address_space(1))) unsigned int*)g,
        (__attribute__((address_space(3))) unsigned int*)l,
        16, 0, 0);
}

__device__ __forceinline__ float sel4(int i, float a, float b, float c, float d){
    float r = (i == 1) ? b : a;
    r = (i == 2) ? c : r;
    r = (i == 3) ? d : r;
    return r;
}

// ---------------- convert f32 -> bf16 (vec4) ----------------
__global__ void cvt4_k(const float* __restrict__ in, ushort* __restrict__ out, int n4){
    int i = blockIdx.x * 256 + threadIdx.x;
    if (i < n4){
        float4 v = ((const float4*)in)[i];
        ushort4 o;
        o.x = f2bf(v.x); o.y = f2bf(v.y); o.z = f2bf(v.z); o.w = f2bf(v.w);
        ((ushort4*)out)[i] = o;
    }
}

__global__ void zero16_k(ushort* __restrict__ p, int n){
    int i = blockIdx.x * 256 + threadIdx.x;
    if (i < n) p[i] = 0;
}

// ---------------- RMSNorm -> bf16 ----------------
__global__ __launch_bounds__(256) void rmsnorm_k(const float* __restrict__ resid,
                                                 const float* __restrict__ norm_w,
                                                 ushort* __restrict__ xn){
    int row = blockIdx.x;
    const float4* r = (const float4*)(resid + (size_t)row * D_);
    float4 v = r[threadIdx.x];
    float ss = v.x*v.x + v.y*v.y + v.z*v.z + v.w*v.w;
    for (int m = 32; m; m >>= 1) ss += __shfl_xor(ss, m);
    __shared__ float sred[4];
    if ((threadIdx.x & 63) == 0) sred[threadIdx.x >> 6] = ss;
    __syncthreads();
    float tot = sred[0] + sred[1] + sred[2] + sred[3];
    float scale = rsqrtf(tot / (float)D_ + 1e-5f);
    const float4* wv = (const float4*)norm_w;
    float4 w = wv[threadIdx.x];
    ushort4 o;
    o.x = f2bf(v.x * scale * w.x);
    o.y = f2bf(v.y * scale * w.y);
    o.z = f2bf(v.z * scale * w.z);
    o.w = f2bf(v.w * scale * w.w);
    ((ushort4*)(xn + (size_t)row * D_))[threadIdx.x] = o;
}

// ---------------- GEMM: C[M,N] = A[M,K] * B[N,K]^T, bf16 in, f32 acc ----------------
// global_load_lds width-16 staging into LINEAR LDS [128][64] (m97 structure).
// EPI: 1 = bf16 store, 3 = acc + aux[idx] f32 store
#define BM 128
#define BN 128
#define BK 64

template<int EPI>
__global__ __launch_bounds__(256)
void gemm_bt(const ushort* __restrict__ A, const ushort* __restrict__ Bm,
             void* __restrict__ Cp, const float* __restrict__ aux,
             int M, int N, int K, int lda, int ldb, int ldc){
    __shared__ __align__(16) ushort As[BM * BK];
    __shared__ __align__(16) ushort Bs[BN * BK];
    const int col0 = blockIdx.x * BN;
    const int row0 = blockIdx.y * BM;
    const int tid = threadIdx.x;
    const int lane = tid & 63;
    const int wid = tid >> 6;
    const int wm = wid >> 1, wn = wid & 1;   // 2x2 waves of 64x64
    f32x4 acc[4][4] = {};

    const int l8 = lane >> 3;        // row within 8-row group
    const int c8 = (lane & 7) * 8;   // col (elements)

    for (int k0 = 0; k0 < K; k0 += BK){
        #pragma unroll
        for (int i = 0; i < 4; ++i){
            const int R0 = wid * 32 + i * 8;   // 8 rows per instr
            gld16(A + (size_t)(row0 + R0 + l8) * lda + k0 + c8, As + R0 * BK);
            gld16(Bm + (size_t)(col0 + R0 + l8) * ldb + k0 + c8, Bs + R0 * BK);
        }
        __syncthreads();   // drains vmcnt before barrier
        #pragma unroll
        for (int kk = 0; kk < 2; ++kk){
            bf16x8 af[4], bfr[4];
            const int krow = lane & 15;
            const int kcol = kk * 32 + (lane >> 4) * 8;
            #pragma unroll
            for (int mi = 0; mi < 4; ++mi)
                af[mi] = *(const bf16x8*)(As + (wm*64 + mi*16 + krow) * BK + kcol);
            #pragma unroll
            for (int ni = 0; ni < 4; ++ni)
                bfr[ni] = *(const bf16x8*)(Bs + (wn*64 + ni*16 + krow) * BK + kcol);
            #pragma unroll
            for (int mi = 0; mi < 4; ++mi)
                #pragma unroll
                for (int ni = 0; ni < 4; ++ni)
                    acc[mi][ni] = __builtin_amdgcn_mfma_f32_16x16x32_bf16(af[mi], bfr[ni], acc[mi][ni], 0, 0, 0);
        }
        __syncthreads();
    }

    #pragma unroll
    for (int mi = 0; mi < 4; ++mi)
        #pragma unroll
        for (int ni = 0; ni < 4; ++ni)
            #pragma unroll
            for (int j = 0; j < 4; ++j){
                int r = row0 + wm*64 + mi*16 + (lane >> 4) * 4 + j;
                int c = col0 + wn*64 + ni*16 + (lane & 15);
                size_t idx = (size_t)r * ldc + c;
                float v = acc[mi][ni][j];
                if (EPI == 1){
                    ((ushort*)Cp)[idx] = f2bf(v);
                } else {
                    ((float*)Cp)[idx] = v + aux[idx];
                }
            }
}

// ---------------- C96 GEMM, split-K: part[ks][4096][128] f32 partials ----------------
__global__ __launch_bounds__(256)
void gemm_c96_sk(const ushort* __restrict__ A, const ushort* __restrict__ Bm,
                 float* __restrict__ part){
    __shared__ __align__(16) ushort As[BM * BK];
    __shared__ __align__(16) ushort Bs[BN * BK];
    const int ks = blockIdx.x;
    const int row0 = blockIdx.y * BM;
    const int tid = threadIdx.x;
    const int lane = tid & 63;
    const int wid = tid >> 6;
    const int wm = wid >> 1, wn = wid & 1;
    f32x4 acc[4][4] = {};
    const int l8 = lane >> 3;
    const int c8 = (lane & 7) * 8;

    for (int k0 = ks * (E_ / KS_); k0 < (ks + 1) * (E_ / KS_); k0 += BK){
        #pragma unroll
        for (int i = 0; i < 4; ++i){
            const int R0 = wid * 32 + i * 8;
            gld16(A + (size_t)(row0 + R0 + l8) * E_ + k0 + c8, As + R0 * BK);
            gld16(Bm + (size_t)(R0 + l8) * E_ + k0 + c8, Bs + R0 * BK);
        }
        __syncthreads();
        #pragma unroll
        for (int kk = 0; kk < 2; ++kk){
            bf16x8 af[4], bfr[4];
            const int krow = lane & 15;
            const int kcol = kk * 32 + (lane >> 4) * 8;
            #pragma unroll
            for (int mi = 0; mi < 4; ++mi)
                af[mi] = *(const bf16x8*)(As + (wm*64 + mi*16 + krow) * BK + kcol);
            #pragma unroll
            for (int ni = 0; ni < 4; ++ni)
                bfr[ni] = *(const bf16x8*)(Bs + (wn*64 + ni*16 + krow) * BK + kcol);
            #pragma unroll
            for (int mi = 0; mi < 4; ++mi)
                #pragma unroll
                for (int ni = 0; ni < 4; ++ni)
                    acc[mi][ni] = __builtin_amdgcn_mfma_f32_16x16x32_bf16(af[mi], bfr[ni], acc[mi][ni], 0, 0, 0);
        }
        __syncthreads();
    }
    float* dst = part + (size_t)ks * M_ * 128;
    #pragma unroll
    for (int mi = 0; mi < 4; ++mi)
        #pragma unroll
        for (int ni = 0; ni < 4; ++ni)
            #pragma unroll
            for (int j = 0; j < 4; ++j){
                int r = row0 + wm*64 + mi*16 + (lane >> 4) * 4 + j;
                int c = wn*64 + ni*16 + (lane & 15);
                dst[(size_t)r * 128 + c] = acc[mi][ni][j];
            }
}

// reduce split-K partials -> C96 bf16; also emit cols 64..95 as f32 (BCf) for the scan
__global__ __launch_bounds__(256) void c96_reduce_k(const float* __restrict__ part,
                                                    ushort* __restrict__ C96,
                                                    float* __restrict__ BCf){
    int i4 = blockIdx.x * 256 + threadIdx.x;     // over M_*128/4
    float4 a = *(const float4*)(part + (size_t)i4 * 4);
    #pragma unroll
    for (int k = 1; k < KS_; ++k){
        float4 b = *(const float4*)(part + (size_t)k * M_ * 128 + (size_t)i4 * 4);
        a.x += b.x; a.y += b.y; a.z += b.z; a.w += b.w;
    }
    ushort4 o;
    o.x = f2bf(a.x); o.y = f2bf(a.y); o.z = f2bf(a.z); o.w = f2bf(a.w);
    *(ushort4*)(C96 + (size_t)i4 * 4) = o;
    int idx = i4 * 4;
    int col = idx & 127;
    int row = idx >> 7;
    if (col >= 64 && col < 96)
        *(float4*)(BCf + (size_t)row * 32 + (col - 64)) = a;
}

// ---------------- causal depthwise conv1d + silu (vec4 along e) ----------------
__global__ __launch_bounds__(256) void conv_silu_k(const ushort* __restrict__ xpre,
                                                   const float* __restrict__ conv_w,
                                                   const float* __restrict__ conv_b,
                                                   float* __restrict__ xf,
                                                   ushort* __restrict__ xb){
    int i4 = blockIdx.x * 256 + threadIdx.x;
    if (i4 >= M_ * E_ / 4) return;
    int idx = i4 * 4;
    int e = idx & (E_ - 1);
    int bl = idx >> 11;
    int t = bl & (L_ - 1);
    float acc[4];
    #pragma unroll
    for (int j = 0; j < 4; ++j) acc[j] = conv_b[e + j];
    #pragma unroll
    for (int k = 0; k < 4; ++k){
        int dt = 3 - k;
        if (t >= dt){
            ushort4 xv = *(const ushort4*)(xpre + idx - dt * E_);
            acc[0] += bf2f(xv.x) * conv_w[(e+0)*4 + k];
            acc[1] += bf2f(xv.y) * conv_w[(e+1)*4 + k];
            acc[2] += bf2f(xv.z) * conv_w[(e+2)*4 + k];
            acc[3] += bf2f(xv.w) * conv_w[(e+3)*4 + k];
        }
    }
    float4 so; ushort4 sb;
    float* sp = (float*)&so;
    #pragma unroll
    for (int j = 0; j < 4; ++j){
        float s = acc[j] / (1.f + __expf(-acc[j]));
        sp[j] = s;
    }
    sb.x = f2bf(so.x); sb.y = f2bf(so.y); sb.z = f2bf(so.z); sb.w = f2bf(so.w);
    *(float4*)(xf + idx) = so;
    *(ushort4*)(xb + idx) = sb;
}

// ---------------- n-in-register chunk-parallel selective scan ----------------
// Thread owns one e, all 16 n-states in registers; wave = one 32-t segment x 64 e.
// Block = 4 waves = 4 consecutive segments; zero block barriers (per-wave staging).
// delta fused via MFMA; output redistributed via 12-shfl rotation (static indices).
// PASS2: y output fused with gating -> y2 bf16.
// NOTE: __launch_bounds__(256,2): the scan state (~140 VGPR) MUST stay register-
// resident; (256,4) capped VGPRs at 64 and spilled everything to scratch
// (428 MB/dispatch HBM scratch traffic, round-6 regression).

template<int PASS2>
__global__ __launch_bounds__(256, 2)
void scan_k(const float* __restrict__ xf, const ushort* __restrict__ C96,
            const float* __restrict__ BCf, const ushort* __restrict__ wd2b,
            const float* __restrict__ wd2_bias, const float* __restrict__ A_log,
            const float* __restrict__ carr,
            float* __restrict__ F, float* __restrict__ segdt,
            const ushort* __restrict__ skipb, const float* __restrict__ W_D,
            ushort* __restrict__ y2)
{
    const int tid = threadIdx.x;
    const int w = tid >> 6, lane = tid & 63;
    const int q = lane >> 4, c = lane & 15;
    const int e0 = blockIdx.x * 64;
    const int g = blockIdx.y;          // seg-group: segs 4g..4g+3, t-window g*128..+128
    const int b = blockIdx.z;
    const int e = e0 + lane;
    const int seg = g * 4 + w;
    const size_t grow0 = (size_t)b * L_ + (size_t)g * 128;   // global row of window start

    __shared__ __align__(16) ushort sxr[128 * 64];   // [r][64]bf16; 16B-chunk XOR-swizzled
    __shared__ __align__(16) float  sBC[128 * 32];   // [r][B n0..15 | C n0..15] f32 linear

    // stage this wave's 32 rows (xr swizzled so MFMA b128 reads are conflict-free)
    #pragma unroll
    for (int k2 = 0; k2 < 4; ++k2){
        int R0 = w * 32 + k2 * 8;
        int r = R0 + (lane >> 3);
        int cc = (lane & 7) ^ (r & 7);
        gld16(C96 + (grow0 + r) * 128 + cc * 8, sxr + R0 * 64);
        gld16(BCf + (grow0 + r) * 32 + (lane & 7) * 4, sBC + R0 * 32);
    }
    asm volatile("s_waitcnt vmcnt(0)" ::: "memory");
    __builtin_amdgcn_sched_barrier(0);

    float Aen[16];
    {
        const float4* al = (const float4*)(A_log + (size_t)e * N_);
        #pragma unroll
        for (int g4 = 0; g4 < 4; ++g4){
            float4 v = al[g4];
            Aen[g4*4+0] = -__expf(v.x); Aen[g4*4+1] = -__expf(v.y);
            Aen[g4*4+2] = -__expf(v.z); Aen[g4*4+3] = -__expf(v.w);
        }
    }
    float h[16];
    if (PASS2){
        const float4* cp = (const float4*)(carr + ((size_t)(b * SSEG + seg) * E_ + e) * N_);
        #pragma unroll
        for (int g4 = 0; g4 < 4; ++g4){
            float4 v = cp[g4];
            h[g4*4+0] = v.x; h[g4*4+1] = v.y; h[g4*4+2] = v.z; h[g4*4+3] = v.w;
        }
    } else {
        #pragma unroll
        for (int n = 0; n < 16; ++n) h[n] = 0.f;
    }

    bf16x8 wfrag[4][2];
    #pragma unroll
    for (int m = 0; m < 4; ++m)
        #pragma unroll
        for (int kk = 0; kk < 2; ++kk)
            wfrag[m][kk] = *(const bf16x8*)(wd2b + (size_t)(e0 + m*16 + c) * DR_ + kk*32 + q*8);

    const float bias_e = wd2_bias[e];
    const float wde = PASS2 ? W_D[e] : 0.f;
    float sdt = 0.f;

    #pragma unroll
    for (int tt = 0; tt < 2; ++tt){
        const int tb = w * 32 + tt * 16;   // window row of tile base
        // --- fused delta: 8 MFMAs, D[t_in][e_in]: lane holds e_in=c, t_in=q*4+j, e-tile m
        f32x4 d0 = {}, d1 = {}, d2 = {}, d3 = {};
        #pragma unroll
        for (int kk = 0; kk < 2; ++kk){
            int r = tb + c;
            int chunk = kk * 4 + q;
            bf16x8 af = *(const bf16x8*)(sxr + r * 64 + ((chunk ^ (r & 7)) << 3));
            d0 = __builtin_amdgcn_mfma_f32_16x16x32_bf16(af, wfrag[0][kk], d0, 0, 0, 0);
            d1 = __builtin_amdgcn_mfma_f32_16x16x32_bf16(af, wfrag[1][kk], d1, 0, 0, 0);
            d2 = __builtin_amdgcn_mfma_f32_16x16x32_bf16(af, wfrag[2][kk], d2, 0, 0, 0);
            d3 = __builtin_amdgcn_mfma_f32_16x16x32_bf16(af, wfrag[3][kk], d3, 0, 0, 0);
        }
        // --- rotation-shuffle: lane l gathers its e's 16 t-values (m = q across quads)
        float rq0[4], rq1[4], rq2[4], rq3[4];
        #pragma unroll
        for (int j = 0; j < 4; ++j) rq0[j] = sel4(q, d0[j], d1[j], d2[j], d3[j]);
        {
            int src1 = (((q + 1) & 3) << 4) + c;
            int pi1 = (q - 1) & 3;
            int src2 = (((q + 2) & 3) << 4) + c;
            int pi2 = (q - 2) & 3;
            int src3 = (((q + 3) & 3) << 4) + c;
            int pi3 = (q - 3) & 3;
            #pragma unroll
            for (int j = 0; j < 4; ++j){
                rq1[j] = __shfl(sel4(pi1, d0[j], d1[j], d2[j], d3[j]), src1);
                rq2[j] = __shfl(sel4(pi2, d0[j], d1[j], d2[j], d3[j]), src2);
                rq3[j] = __shfl(sel4(pi3, d0[j], d1[j], d2[j], d3[j]), src3);
            }
        }
        // --- reorder to t-order + softplus (all static indices)
        float dts[16];
        #pragma unroll
        for (int p = 0; p < 4; ++p){
            int sp = (p - q) & 3;
            #pragma unroll
            for (int j = 0; j < 4; ++j){
                float z = sel4(sp, rq0[j], rq1[j], rq2[j], rq3[j]) + bias_e;
                float dt = (z > 20.f) ? z : log1pf(__expf(z));
                dts[p*4+j] = dt;
                if (!PASS2) sdt += dt;
            }
        }
        // --- scan 16 timesteps
        const float* xp = xf + (grow0 + tb) * E_ + e;
        const ushort* skp = skipb + (grow0 + tb) * E_ + e;
        ushort* yp = y2 + (grow0 + tb) * E_ + e;
        #pragma unroll
        for (int u = 0; u < 16; ++u){
            const float* bc = sBC + (tb + u) * 32;
            float dt = dts[u];
            float xu = xp[(size_t)u * E_];
            float dtx = dt * xu;
            float y0 = 0.f, y1 = 0.f;
            #pragma unroll
            for (int gg = 0; gg < 4; ++gg){
                float4 Bv = *(const float4*)(bc + gg * 4);
                h[gg*4+0] = __expf(dt * Aen[gg*4+0]) * h[gg*4+0] + dtx * Bv.x;
                h[gg*4+1] = __expf(dt * Aen[gg*4+1]) * h[gg*4+1] + dtx * Bv.y;
                h[gg*4+2] = __expf(dt * Aen[gg*4+2]) * h[gg*4+2] + dtx * Bv.z;
                h[gg*4+3] = __expf(dt * Aen[gg*4+3]) * h[gg*4+3] + dtx * Bv.w;
                if (PASS2){
                    float4 Cv = *(const float4*)(bc + 16 + gg * 4);
                    y0 += h[gg*4+0] * Cv.x + h[gg*4+1] * Cv.y;
                    y1 += h[gg*4+2] * Cv.z + h[gg*4+3] * Cv.w;
                }
            }
            if (PASS2){
                float sk = bf2f(skp[(size_t)u * E_]);
                float gsk = sk / (1.f + __expf(-sk));
                float yo = (y0 + y1 + wde * xu) * gsk;
                yp[(size_t)u * E_] = f2bf(yo);
            }
        }
    }
    if (!PASS2){
        float* Fp = F + ((size_t)(b * SSEG + seg) * E_ + e) * N_;
        #pragma unroll
        for (int g4 = 0; g4 < 4; ++g4){
            float4 v;
            v.x = h[g4*4+0]; v.y = h[g4*4+1]; v.z = h[g4*4+2]; v.w = h[g4*4+3];
            ((float4*)Fp)[g4] = v;
        }
        segdt[(size_t)(b * SSEG + seg) * E_ + e] = sdt;
    }
}

// sequential carry over SSEG segments per (b,e,n)
__global__ __launch_bounds__(256) void carry_k(const float* __restrict__ F,
                                               const float* __restrict__ segdt,
                                               const float* __restrict__ A_log,
                                               float* __restrict__ carr){
    int idx = blockIdx.x * 256 + threadIdx.x;      // over B_*E_*N_
    int n = idx & 15;
    int e = (idx >> 4) & (E_ - 1);
    int b = idx >> 15;
    const float Aen = -__expf(A_log[e * N_ + n]);
    float cacc = 0.f;
    for (int s = 0; s < SSEG; ++s){
        size_t base = ((size_t)(b * SSEG + s) * E_ + e) * N_ + n;
        carr[base] = cacc;
        float P = __expf(Aen * segdt[(size_t)(b * SSEG + s) * E_ + e]);
        cacc = P * cacc + F[base];
    }
}

// ---------------- launch ----------------
extern "C" void kernel_launch(void* const* d_in, const int* in_sizes, int n_in,
                              void* d_out, int out_size, void* d_ws, size_t ws_size,
                              hipStream_t stream){
    const float* resid  = (const float*)d_in[0];
    const float* norm_w = (const float*)d_in[1];
    const float* skip_w = (const float*)d_in[2];
    const float* in_w   = (const float*)d_in[3];
    const float* conv_w = (const float*)d_in[4];
    const float* conv_b = (const float*)d_in[5];
    const float* wd1    = (const float*)d_in[6];
    const float* wd2    = (const float*)d_in[7];
    const float* wd2_b  = (const float*)d_in[8];
    const float* wB     = (const float*)d_in[9];
    const float* wC     = (const float*)d_in[10];
    const float* A_log  = (const float*)d_in[11];
    const float* W_D    = (const float*)d_in[12];
    const float* out_w  = (const float*)d_in[13];
    float* out = (float*)d_out;

    char* ws = (char*)d_ws;
    size_t off = 0;
    auto alloc = [&](size_t bytes) -> char* {
        char* p = ws + off;
        off += (bytes + 255) & ~(size_t)255;
        return p;
    };
    // --- aliased region (32MB): wi, wsk, xn, xpre dead in stages; reused for
    //     split-K partials (16MB, dead after c96_reduce) then carr (16MB).
    char* alias_base = ws;
    ushort* wi_b    = (ushort*)alloc((size_t)E_ * D_ * 2);   // 4MB
    ushort* wsk_b   = (ushort*)alloc((size_t)E_ * D_ * 2);   // 4MB
    ushort* xn_b    = (ushort*)alloc((size_t)M_ * D_ * 2);   // 8MB
    ushort* xpre_b  = (ushort*)alloc((size_t)M_ * E_ * 2);   // 16MB
    float*  part_buf= (float*)alias_base;                    // 16MB alias (KS_*M_*128*4)
    float*  carr_buf= (float*)alias_base;                    // 16MB alias (after c96_reduce)
    // --- persistent buffers
    ushort* wo_b    = (ushort*)alloc((size_t)D_ * E_ * 2);       // 4MB
    ushort* wd2_bf  = (ushort*)alloc((size_t)E_ * DR_ * 2);      // 256KB
    ushort* W96_b   = (ushort*)alloc((size_t)128 * E_ * 2);      // 512KB
    ushort* skip_b  = (ushort*)alloc((size_t)M_ * E_ * 2);       // 16MB
    float*  xff     = (float*)alloc((size_t)M_ * E_ * 4);        // 32MB
    ushort* xb_b    = (ushort*)alloc((size_t)M_ * E_ * 2);       // 16MB
    ushort* C96_b   = (ushort*)alloc((size_t)M_ * 128 * 2);      // 1MB
    float*  scr     = (float*)alloc((size_t)M_ * E_ * 4);        // 32MB scratch slot
    ushort* y2_b    = (ushort*)alloc((size_t)M_ * E_ * 2);       // 16MB
    // sub-layout of scr: F (16MB) | segdt (1MB) | BCf (512KB)
    float* F_buf    = scr;
    float* segdt_buf= scr + (size_t)B_ * SSEG * E_ * N_;
    float* BCf_buf  = segdt_buf + (size_t)B_ * SSEG * E_;
    (void)ws_size; (void)in_sizes; (void)n_in; (void)out_size;

    const int thr = 256;
    auto blocks4 = [](int n){ return (n/4 + 255) / 256; };

    // weight conversions
    cvt4_k<<<blocks4(E_*D_), thr, 0, stream>>>(in_w,   wi_b,   E_*D_/4);
    cvt4_k<<<blocks4(E_*D_), thr, 0, stream>>>(skip_w, wsk_b,  E_*D_/4);
    cvt4_k<<<blocks4(D_*E_), thr, 0, stream>>>(out_w,  wo_b,   D_*E_/4);
    cvt4_k<<<blocks4(E_*DR_), thr, 0, stream>>>(wd2,   wd2_bf, E_*DR_/4);
    cvt4_k<<<blocks4(DR_*E_), thr, 0, stream>>>(wd1,   W96_b,            DR_*E_/4);
    cvt4_k<<<blocks4(N_*E_),  thr, 0, stream>>>(wB,    W96_b + 64*E_,    N_*E_/4);
    cvt4_k<<<blocks4(N_*E_),  thr, 0, stream>>>(wC,    W96_b + 80*E_,    N_*E_/4);
    zero16_k<<<(32*E_ + 255)/256, thr, 0, stream>>>(W96_b + 96*E_, 32*E_);

    // RMSNorm
    rmsnorm_k<<<M_, thr, 0, stream>>>(resid, norm_w, xn_b);

    // in-proj and skip-proj GEMMs: [4096,2048] = [4096,1024] x [2048,1024]^T
    gemm_bt<1><<<dim3(E_/BN, M_/BM), thr, 0, stream>>>(xn_b, wi_b,  xpre_b, nullptr, M_, E_, D_, D_, D_, E_);
    gemm_bt<1><<<dim3(E_/BN, M_/BM), thr, 0, stream>>>(xn_b, wsk_b, skip_b, nullptr, M_, E_, D_, D_, D_, E_);

    // conv + silu
    conv_silu_k<<<(M_*E_/4 + 255)/256, thr, 0, stream>>>(xpre_b, conv_w, conv_b, xff, xb_b);

    // C96[4096,128] = x[4096,2048] x W96[128,2048]^T, split-K x8 + reduce (+BCf f32)
    gemm_c96_sk<<<dim3(KS_, M_/BM), thr, 0, stream>>>(xb_b, W96_b, part_buf);
    c96_reduce_k<<<(M_*128/4)/256, thr, 0, stream>>>(part_buf, C96_b, BCf_buf);

    // chunk-parallel selective scan (n-in-register), gate fused into pass 2
    scan_k<0><<<dim3(E_/64, 16, B_), thr, 0, stream>>>(xff, C96_b, BCf_buf, wd2_bf, wd2_b, A_log,
                                                       nullptr, F_buf, segdt_buf, nullptr, nullptr, nullptr);
    carry_k<<<(B_*E_*N_)/256, thr, 0, stream>>>(F_buf, segdt_buf, A_log, carr_buf);
    scan_k<1><<<dim3(E_/64, 16, B_), thr, 0, stream>>>(xff, C96_b, BCf_buf, wd2_bf, wd2_b, A_log,
                                                       carr_buf, nullptr, nullptr, skip_b, W_D, y2_b);

    // out-proj + residual: out[4096,1024] = y2[4096,2048] x out_w[1024,2048]^T + resid
    gemm_bt<3><<<dim3(D_/BN, M_/BM), thr, 0, stream>>>(y2_b, wo_b, out, resid, M_, D_, E_, E_, E_, D_);
}